// Round 9
// baseline (195.946 us; speedup 1.0000x reference)
//
#include <hip/hip_runtime.h>
#include <stdint.h>

#define N_ROWS 262144
#define D_OUTC 128
#define M_MOD  64
#define T_CTX  16

// ---- workspace layout (bytes) ----
#define WT_OFF   ((size_t)0)
#define WT_BYTES ((size_t)T_CTX * N_ROWS * 2)          // Wt[t][n] f16  8.4MB
#define SS_OFF   (WT_OFF + WT_BYTES)
#define SS_BYTES ((size_t)T_CTX * M_MOD * M_MOD * 4)
#define B_OFF    (SS_OFF + SS_BYTES)
#define B_BYTES  ((size_t)T_CTX * M_MOD * 4)
#define WSUM_OFF (B_OFF + B_BYTES)
#define WSUM_BYTES ((size_t)64)
#define LT_OFF   (WSUM_OFF + WSUM_BYTES)
#define LT_BYTES ((size_t)64)
#define PSS_OFF  (LT_OFF + LT_BYTES)
#define PSS_BYTES ((size_t)256 * T_CTX * M_MOD * M_MOD * 2)  // 33.5MB bf16 partials
#define NEED_BIG (PSS_OFF + PSS_BYTES)

typedef __attribute__((ext_vector_type(4))) float f32x4;
typedef __attribute__((ext_vector_type(8))) _Float16 f16x8;
typedef __attribute__((ext_vector_type(2))) _Float16 h2;

union FR { uint4 u; f16x8 v; h2 h[4]; };

__device__ __forceinline__ float bf2f(unsigned short u) {
  return __uint_as_float(((unsigned int)u) << 16);
}
__device__ __forceinline__ unsigned short f2bf(float f) {
  unsigned int x = __float_as_uint(f);
  return (unsigned short)((x + 0x7fffu + ((x >> 16) & 1u)) >> 16);
}
__device__ __forceinline__ h2 cvt_pkrtz(float a, float b) {
  return __builtin_bit_cast(h2, __builtin_amdgcn_cvt_pkrtz(a, b));
}

#define WAITVM(N) asm volatile("s_waitcnt vmcnt(" #N ")" ::: "memory")
#define WAITLG()  asm volatile("s_waitcnt lgkmcnt(0)" ::: "memory")
#define SBAR() do { __builtin_amdgcn_s_barrier(); __builtin_amdgcn_sched_barrier(0); } while (0)

// ================ wtr: W[N][16] f32 -> Wt[16][N] f16, + wsum fold ================
__global__ __launch_bounds__(256) void wtr_kernel(const float* __restrict__ W,
                                                  _Float16* __restrict__ Wt,
                                                  float* __restrict__ wsum)
{
  __shared__ float Wf[16][260];
  const int tid = threadIdx.x;
  const int n0  = blockIdx.x * 256;
  {
    const float4* src = (const float4*)(W + (size_t)(n0 + tid) * T_CTX);
#pragma unroll
    for (int q = 0; q < 4; ++q) {
      float4 v = src[q];
      Wf[q * 4 + 0][tid] = v.x; Wf[q * 4 + 1][tid] = v.y;
      Wf[q * 4 + 2][tid] = v.z; Wf[q * 4 + 3][tid] = v.w;
    }
  }
  __syncthreads();
  const int t = tid >> 4, c0 = (tid & 15) * 16;
  FR o[2];
  float s = 0.f;
#pragma unroll
  for (int j = 0; j < 2; ++j)
#pragma unroll
    for (int p = 0; p < 4; ++p) {
      float a = Wf[t][c0 + j * 8 + 2 * p], b = Wf[t][c0 + j * 8 + 2 * p + 1];
      o[j].h[p] = cvt_pkrtz(a, b);
      s += a + b;
    }
  uint4* dst = (uint4*)(Wt + (size_t)t * N_ROWS + n0 + c0);
  dst[0] = o[0].u; dst[1] = o[1].u;
  s += __shfl_xor(s, 1); s += __shfl_xor(s, 2);
  s += __shfl_xor(s, 4); s += __shfl_xor(s, 8);
  if ((tid & 15) == 0) atomicAdd(&wsum[t], s);
}

// ================ fused: produce Z-tile (MFMA) -> LDS -> consume SS/B (MFMA) ====
// grid 256 (1 block/CU, ns = blockIdx), 1024 thr = 16 waves.
// per 64-n chunk: produce: wave (mq=wv&3,nq=wv>>2) computes one 16x16 Z^T tile;
// consume: wave wv = ctx. One barrier per chunk; Y dbuf gload_lds, vmcnt(2).
#define NCH 16
template <bool PARTIAL>
__global__ __launch_bounds__(1024, 4) void fuse_kernel(
    const float* __restrict__ Y, const float* __restrict__ Mp,
    const _Float16* __restrict__ Wt,
    float* __restrict__ SS, float* __restrict__ Bm,
    unsigned short* __restrict__ Pss)
{
  __shared__ __align__(16) float    Yl[2][64 * 128];   // 2 x 32KB, 512B/row, slots swizzled
  __shared__ __align__(16) _Float16 Zl[2][64 * 64];    // 2 x 8KB, 128B/row, slots swizzled
  __shared__ __align__(16) _Float16 Mpl[64 * 128];     // 16KB, 256B/row, slots swizzled
  __shared__ __align__(16) _Float16 Wlds[16 * 1024];   // 32KB, [t][1024 n] linear
  const int tid = threadIdx.x;
  const int l   = tid & 63;
  const int wv  = tid >> 6;          // 0..15 : producer tile id / consumer ctx
  const int g   = l >> 4;
  const int col = l & 15;
  const int ns  = blockIdx.x;
  const int n0b = ns * 1024;
  const int mq  = wv & 3, nq = wv >> 2;

  f32x4 acc[4][4];
  f32x4 accB[4];
#pragma unroll
  for (int a = 0; a < 4; ++a) {
    accB[a] = (f32x4){0.f, 0.f, 0.f, 0.f};
#pragma unroll
    for (int b = 0; b < 4; ++b) acc[a][b] = (f32x4){0.f, 0.f, 0.f, 0.f};
  }
  FR ones;
#pragma unroll
  for (int j = 0; j < 4; ++j) ones.h[j] = (h2){(_Float16)1.f, (_Float16)1.f};

  // ---- Mpl: f32 -> f16 swizzled (1024 thr x 1 slot) ----
  {
    const int m = tid >> 4;        // 0..63
    const int s = tid & 15;        // 16B f16 slot (8 d's)
    const float* mp = Mp + (size_t)m * D_OUTC + s * 8;
    float4 a = *(const float4*)mp;
    float4 b = *(const float4*)(mp + 4);
    FR o;
    o.h[0] = cvt_pkrtz(a.x, a.y); o.h[1] = cvt_pkrtz(a.z, a.w);
    o.h[2] = cvt_pkrtz(b.x, b.y); o.h[3] = cvt_pkrtz(b.z, b.w);
    const int ss2 = (s & ~7) | ((s & 7) ^ (m & 7));
    *(uint4*)((char*)Mpl + m * 256 + ss2 * 16) = o.u;
  }
  // ---- W stage: 32KB via gload_lds (2 x 16B per thread) ----
#pragma unroll
  for (int j = 0; j < 2; ++j) {
    const int o = j * 16384 + tid * 16;        // dest byte (wave-uniform base + l*16)
    const int t = o >> 11;
    const int noff = (o & 2047) >> 1;
    const _Float16* src = Wt + (size_t)t * N_ROWS + n0b + noff;
    __builtin_amdgcn_global_load_lds((const unsigned int*)src,
        (unsigned int*)((char*)Wlds + o), 16, 0, 0);
  }
  // ---- Y stage: 32KB per chunk (2 x 16B per thread), inverse-swizzled source ----
  auto stageY = [&](int c) {
    const int nb = n0b + c * 64;
#pragma unroll
    for (int j = 0; j < 2; ++j) {
      const int o = j * 16384 + tid * 16;      // byte in 32KB buffer
      const int r = o >> 9;                    // row 0..63
      const int qp = (o >> 4) & 31;            // lds slot
      const int q = (qp & ~7) | ((qp & 7) ^ (r & 7));
      const float* src = Y + (size_t)(nb + r) * D_OUTC + q * 4;
      __builtin_amdgcn_global_load_lds((const unsigned int*)src,
          (unsigned int*)((char*)&Yl[c & 1][0] + o), 16, 0, 0);
    }
  };
  // ---- producer: one 16x16 Z^T tile per wave ----
  auto produce = [&](int c) {
    const char* yb = (const char*)&Yl[c & 1][0];
    const int rB = nq * 16 + col;              // Y row in chunk
    f32x4 pacc = (f32x4){0.f, 0.f, 0.f, 0.f};
#pragma unroll
    for (int ks = 0; ks < 4; ++ks) {
      const int q0 = ks * 8 + 2 * g;
      const int q1 = q0 + 1;
      uint4 y0 = *(const uint4*)(yb + rB * 512 + 16 * ((q0 & ~7) | ((q0 & 7) ^ (rB & 7))));
      uint4 y1 = *(const uint4*)(yb + rB * 512 + 16 * ((q1 & ~7) | ((q1 & 7) ^ (rB & 7))));
      const float* f0 = (const float*)&y0;
      const float* f1 = (const float*)&y1;
      FR B;
      B.h[0] = cvt_pkrtz(f0[0], f0[1]); B.h[1] = cvt_pkrtz(f0[2], f0[3]);
      B.h[2] = cvt_pkrtz(f1[0], f1[1]); B.h[3] = cvt_pkrtz(f1[2], f1[3]);
      const int mA = mq * 16 + col;
      const int s2 = ks * 4 + g;
      FR A;
      A.u = *(const uint4*)((char*)Mpl + mA * 256 + 16 * ((s2 & ~7) | ((s2 & 7) ^ (mA & 7))));
      pacc = __builtin_amdgcn_mfma_f32_16x16x32_f16(A.v, B.v, pacc, 0, 0, 0);
    }
    char* zb = (char*)&Zl[c & 1][0];
#pragma unroll
    for (int i = 0; i < 4; ++i) {
      const int rm = mq * 16 + g * 4 + i;      // Z^T row (m)
      const int sn = nq * 2 + (col >> 3);      // 16B slot (n/8)
      const int by = rm * 128 + 16 * (sn ^ (rm & 7)) + (col & 7) * 2;
      *(_Float16*)(zb + by) = (_Float16)pacc[i];
    }
  };
  // ---- consumer: wave = ctx; 40 MFMA per chunk ----
  auto consume = [&](int c) {
    const char* zb = (const char*)&Zl[c & 1][0];
    const char* wb = (const char*)Wlds + wv * 2048 + c * 128;
#pragma unroll
    for (int s = 0; s < 2; ++s) {
      FR wfr;
      wfr.u = *(const uint4*)(wb + s * 64 + g * 16);
      FR fr[4];
#pragma unroll
      for (int qi = 0; qi < 4; ++qi) {
        const int r = qi * 16 + col;
        fr[qi].u = *(const uint4*)(zb + r * 128 + 16 * ((s * 4 + g) ^ (r & 7)));
      }
      __builtin_amdgcn_s_setprio(1);
#pragma unroll
      for (int qi = 0; qi < 4; ++qi) {
        FR A;
#pragma unroll
        for (int j = 0; j < 4; ++j) A.h[j] = fr[qi].h[j] * wfr.h[j];
        accB[qi] = __builtin_amdgcn_mfma_f32_16x16x32_f16(A.v, ones.v, accB[qi], 0, 0, 0);
#pragma unroll
        for (int ki = 0; ki < 4; ++ki)
          acc[qi][ki] = __builtin_amdgcn_mfma_f32_16x16x32_f16(A.v, fr[ki].v, acc[qi][ki], 0, 0, 0);
      }
      __builtin_amdgcn_s_setprio(0);
    }
  };

  // ---- prologue ----
  stageY(0);
  stageY(1);
  WAITLG();            // Mpl ds_writes done (own)
  WAITVM(2);           // W + Y0 resident; Y1 in flight
  SBAR();

  for (int c = 0; c < NCH - 2; ++c) {
    if (c) WAITVM(2);  // Y[c] resident (oldest-first drain); stage(c+1) may stay in flight
    produce(c);
    WAITLG();          // own Zl ds_writes done
    SBAR();            // Zl[c] ready; Y[c] fully read by all
    stageY(c + 2);     // refill Y[c&1]
    consume(c);
  }
  // c = 14
  WAITVM(2); produce(14); WAITLG(); SBAR(); consume(14);
  // c = 15
  WAITVM(0); produce(15); WAITLG(); SBAR(); consume(15);

  // ---- B out: lanes col==0 hold rows g*4+i of each qi tile ----
  if (col == 0) {
#pragma unroll
    for (int qi = 0; qi < 4; ++qi)
#pragma unroll
      for (int i = 0; i < 4; ++i)
        atomicAdd(&Bm[wv * 64 + qi * 16 + g * 4 + i], accB[qi][i]);
  }
  // ---- SS tiles out ----
  if (PARTIAL) {
    unsigned short* P = Pss + ((size_t)ns * 16 + wv) * 4096;
#pragma unroll
    for (int qi = 0; qi < 4; ++qi)
#pragma unroll
      for (int ki = 0; ki < 4; ++ki)
#pragma unroll
        for (int i = 0; i < 4; ++i)
          P[(qi * 16 + g * 4 + i) * 64 + ki * 16 + col] = f2bf(acc[qi][ki][i]);
  } else {
#pragma unroll
    for (int qi = 0; qi < 4; ++qi)
#pragma unroll
      for (int ki = 0; ki < 4; ++ki)
#pragma unroll
        for (int i = 0; i < 4; ++i)
          atomicAdd(&SS[(size_t)wv * 4096 + (qi * 16 + g * 4 + i) * 64 + ki * 16 + col],
                    acc[qi][ki][i]);
  }
}

// ================ reduce bf16 partials -> SS f32 ================
__global__ __launch_bounds__(256) void ssred_kernel(
    const unsigned short* __restrict__ Pss, float* __restrict__ SS)
{
  const int e = blockIdx.x * 256 + threadIdx.x;
  float s = 0.f;
#pragma unroll 8
  for (int b = 0; b < 256; ++b)
    s += bf2f(Pss[(size_t)b * 65536 + e]);
  SS[e] = s;
}

// ================ finalize ================
__global__ __launch_bounds__(64) void fin1_kernel(
    const float* __restrict__ SS, const float* __restrict__ Bm,
    const float* __restrict__ wsum, const float* __restrict__ Cp,
    const float* __restrict__ emaS, const unsigned char* __restrict__ inited,
    float* __restrict__ LT)
{
  const int t = blockIdx.x, m = threadIdx.x;
  __shared__ float muL[64], stdL[64];
  const float ws  = wsum[t];
  const float inv = 1.0f / ws;
  const float mu  = Bm[t * 64 + m] * inv;
  {
    float Smm = SS[(size_t)t * 4096 + m * 65] * inv - mu * mu;
    float de  = 0.9f * emaS[(size_t)t * 4096 + m * 65] + 0.1f * Smm;
    float sq  = inited[t] ? de : Smm;
    muL[m]  = mu;
    stdL[m] = sqrtf(sq + 1e-6f);
  }
  __syncthreads();
  const float sm = stdL[m];
  const float* SSr = SS + (size_t)t * 4096 + m * 64;
  const float* Cpr = Cp + (size_t)t * 4096 + m * 64;
  float acc = 0.f;
#pragma unroll
  for (int k = 0; k < 64; ++k) {
    float Sig = SSr[k] * inv - mu * muL[k];
    float den = sm * stdL[k] + 1e-6f;
    float ch  = fminf(1.f, fmaxf(-1.f, Sig / den));
    float d   = ch - Cpr[k];
    acc = fmaf(d, d, acc);
  }
#pragma unroll
  for (int o = 1; o < 64; o <<= 1) acc += __shfl_xor(acc, o);
  if (m == 0) LT[t] = acc * inv;
}

__global__ __launch_bounds__(64) void fin2_kernel(
    const float* __restrict__ LT, const float* __restrict__ wsum,
    float* __restrict__ out)
{
  const int l = threadIdx.x;
  float lt = 0.f, act = 0.f;
  if (l < 16) {
    float ws = wsum[l];
    if (ws >= 30.0f) { act = 1.f; lt = LT[l]; }
  }
#pragma unroll
  for (int o = 1; o < 16; o <<= 1) {
    lt  += __shfl_xor(lt, o);
    act += __shfl_xor(act, o);
  }
  if (l == 0) out[0] = (act > 0.f) ? (0.1f * 1.0f * lt / act) : 0.f;
}

extern "C" void kernel_launch(void* const* d_in, const int* in_sizes, int n_in,
                              void* d_out, int out_size, void* d_ws, size_t ws_size,
                              hipStream_t stream) {
  (void)in_sizes; (void)n_in; (void)out_size;
  const float* Y    = (const float*)d_in[0];
  const float* W    = (const float*)d_in[1];
  const float* Mp   = (const float*)d_in[2];
  const float* Cp   = (const float*)d_in[3];
  const float* emaS = (const float*)d_in[4];
  const unsigned char* inited = (const unsigned char*)d_in[6];
  float* out = (float*)d_out;
  char* ws = (char*)d_ws;
  _Float16* Wt  = (_Float16*)(ws + WT_OFF);
  float* SS   = (float*)(ws + SS_OFF);
  float* Bm   = (float*)(ws + B_OFF);
  float* wsum = (float*)(ws + WSUM_OFF);
  float* LT   = (float*)(ws + LT_OFF);
  unsigned short* Pss = (unsigned short*)(ws + PSS_OFF);

  if (ws_size >= NEED_BIG) {
    (void)hipMemsetAsync(ws + B_OFF, 0, B_BYTES + WSUM_BYTES, stream);
    wtr_kernel<<<N_ROWS / 256, 256, 0, stream>>>(W, Wt, wsum);
    fuse_kernel<true><<<256, 1024, 0, stream>>>(Y, Mp, Wt, SS, Bm, Pss);
    ssred_kernel<<<256, 256, 0, stream>>>(Pss, SS);
  } else {
    (void)hipMemsetAsync(ws + SS_OFF, 0, SS_BYTES + B_BYTES + WSUM_BYTES, stream);
    wtr_kernel<<<N_ROWS / 256, 256, 0, stream>>>(W, Wt, wsum);
    fuse_kernel<false><<<256, 1024, 0, stream>>>(Y, Mp, Wt, SS, Bm, Pss);
  }
  fin1_kernel<<<16, 64, 0, stream>>>(SS, Bm, wsum, Cp, emaS, inited, LT);
  fin2_kernel<<<1, 64, 0, stream>>>(LT, wsum, out);
}

// Round 10
// 152.577 us; speedup vs baseline: 1.2842x; 1.2842x over previous
//
#include <hip/hip_runtime.h>
#include <stdint.h>

#define N_ROWS 262144
#define D_OUTC 128
#define M_MOD  64
#define T_CTX  16

// ---- workspace layout (bytes) ----
#define ZB_OFF   ((size_t)0)
#define ZB_BYTES ((size_t)M_MOD * N_ROWS * 2)          // Zbt[m][n] f16  33.5MB
#define WT_OFF   (ZB_OFF + ZB_BYTES)
#define WT_BYTES ((size_t)T_CTX * N_ROWS * 2)          // Wt[t][n] f16  8.4MB
#define SS_OFF   (WT_OFF + WT_BYTES)
#define SS_BYTES ((size_t)T_CTX * M_MOD * M_MOD * 4)
#define B_OFF    (SS_OFF + SS_BYTES)
#define B_BYTES  ((size_t)T_CTX * M_MOD * 4)
#define WSUM_OFF (B_OFF + B_BYTES)
#define WSUM_BYTES ((size_t)1024)                      // wsum[t] at stride 16 f32 (64B lines)
#define LT_OFF   (WSUM_OFF + WSUM_BYTES)
#define LT_BYTES ((size_t)64)
#define PSS_OFF  (LT_OFF + LT_BYTES)
#define PSS_BYTES ((size_t)256 * T_CTX * M_MOD * M_MOD * 2)  // 33.5MB bf16 partials
#define NEED_BIG (PSS_OFF + PSS_BYTES)

typedef __attribute__((ext_vector_type(4))) float f32x4;
typedef __attribute__((ext_vector_type(8))) _Float16 f16x8;
typedef __attribute__((ext_vector_type(2))) _Float16 h2;

union FR { uint4 u; f16x8 v; h2 h[4]; };

__device__ __forceinline__ float bf2f(unsigned short u) {
  return __uint_as_float(((unsigned int)u) << 16);
}
__device__ __forceinline__ unsigned short f2bf(float f) {
  unsigned int x = __float_as_uint(f);
  return (unsigned short)((x + 0x7fffu + ((x >> 16) & 1u)) >> 16);
}
__device__ __forceinline__ h2 cvt_pkrtz(float a, float b) {
  return __builtin_bit_cast(h2, __builtin_amdgcn_cvt_pkrtz(a, b));
}

#define WAITVM(N) asm volatile("s_waitcnt vmcnt(" #N ")" ::: "memory")
#define SBAR() do { __builtin_amdgcn_s_barrier(); __builtin_amdgcn_sched_barrier(0); } while (0)

// ================ zkw: Z^T f16 (coalesced), Wt f16, wsum ================
// 2048 blocks x 256 thr (4 waves), 128 n per block (2 tiles of 64).
// Y read direct-to-register (coalesced float4). LDS: Mpl (swizzled f16) + Wf.
__global__ __launch_bounds__(256, 4) void zkw_kernel(
    const float* __restrict__ Y, const float* __restrict__ Mp,
    const float* __restrict__ W,
    _Float16* __restrict__ Zbt, _Float16* __restrict__ Wt,
    float* __restrict__ wsum)
{
  __shared__ __align__(16) _Float16 Mpl[64 * 128];  // 256B/row, 16B slots swizzled by m&7
  __shared__ float Wf[16][132];
  const int tid = threadIdx.x;
  const int l   = tid & 63;
  const int wv  = tid >> 6;
  const int g   = l >> 4;
  const int col = l & 15;
  const int n0  = blockIdx.x * 128;

  // ---- Mpl: f32 -> f16 swizzled ----
  {
    const int m  = tid >> 2;
    const int dq = tid & 3;
#pragma unroll
    for (int i = 0; i < 4; ++i) {
      const int s = dq * 4 + i;
      const float* mp = Mp + (size_t)m * D_OUTC + s * 8;
      float4 a = *(const float4*)mp;
      float4 b = *(const float4*)(mp + 4);
      FR o;
      o.h[0] = cvt_pkrtz(a.x, a.y); o.h[1] = cvt_pkrtz(a.z, a.w);
      o.h[2] = cvt_pkrtz(b.x, b.y); o.h[3] = cvt_pkrtz(b.z, b.w);
      const int ss2 = (s & ~7) | ((s & 7) ^ (m & 7));
      *(uint4*)((char*)Mpl + m * 256 + ss2 * 16) = o.u;
    }
  }
  // ---- W slice transpose into Wf: 128 rows x 16 ----
  {
    const int r  = tid >> 1;
    const int hh = (tid & 1) * 8;
    const float* wr = W + (size_t)(n0 + r) * T_CTX + hh;
    float4 a = *(const float4*)wr;
    float4 b = *(const float4*)(wr + 4);
    Wf[hh + 0][r] = a.x; Wf[hh + 1][r] = a.y; Wf[hh + 2][r] = a.z; Wf[hh + 3][r] = a.w;
    Wf[hh + 4][r] = b.x; Wf[hh + 5][r] = b.y; Wf[hh + 6][r] = b.z; Wf[hh + 7][r] = b.w;
  }
  __syncthreads();
  // ---- Wt out (uint4 per thread) + wsum fold ----
  {
    const int t = tid >> 4, seg = tid & 15;
    float v[8];
#pragma unroll
    for (int p = 0; p < 8; ++p) v[p] = Wf[t][seg * 8 + p];
    FR o;
#pragma unroll
    for (int p = 0; p < 4; ++p) o.h[p] = cvt_pkrtz(v[2 * p], v[2 * p + 1]);
    *(uint4*)(Wt + (size_t)t * N_ROWS + n0 + seg * 8) = o.u;
    float s = ((v[0] + v[1]) + (v[2] + v[3])) + ((v[4] + v[5]) + (v[6] + v[7]));
    s += __shfl_xor(s, 1); s += __shfl_xor(s, 2);
    s += __shfl_xor(s, 4); s += __shfl_xor(s, 8);
    if ((l & 15) == 0) atomicAdd(&wsum[t * 16], s);
  }
  // ---- main: 2 tiles of 64 n ----
#pragma unroll
  for (int it = 0; it < 2; ++it) {
    const int nt = n0 + it * 64 + wv * 16;     // tile n-base for this wave
    const float* __restrict__ yr = Y + (size_t)(nt + col) * D_OUTC;
    float4 yv[8];
#pragma unroll
    for (int ks = 0; ks < 4; ++ks) {
      yv[2 * ks]     = *(const float4*)(yr + ks * 32 + g * 8);
      yv[2 * ks + 1] = *(const float4*)(yr + ks * 32 + g * 8 + 4);
    }
    f32x4 acc[4];
#pragma unroll
    for (int qi = 0; qi < 4; ++qi) acc[qi] = (f32x4){0.f, 0.f, 0.f, 0.f};
#pragma unroll
    for (int ks = 0; ks < 4; ++ks) {
      const float* f0 = (const float*)&yv[2 * ks];
      const float* f1 = (const float*)&yv[2 * ks + 1];
      FR Yf;
      Yf.h[0] = cvt_pkrtz(f0[0], f0[1]); Yf.h[1] = cvt_pkrtz(f0[2], f0[3]);
      Yf.h[2] = cvt_pkrtz(f1[0], f1[1]); Yf.h[3] = cvt_pkrtz(f1[2], f1[3]);
#pragma unroll
      for (int qi = 0; qi < 4; ++qi) {
        const int m = qi * 16 + col;
        const int s = ks * 4 + g;
        FR Mf;
        Mf.u = *(const uint4*)((char*)Mpl + m * 256 + 16 * ((s & ~7) | ((s & 7) ^ (m & 7))));
        // A = Y rows (n), B = Mp cols (m)  ->  C[n][m]
        acc[qi] = __builtin_amdgcn_mfma_f32_16x16x32_f16(Yf.v, Mf.v, acc[qi], 0, 0, 0);
      }
    }
    // lane (g,col) reg i holds Z[n = nt + g*4 + i][m = qi*16 + col] -> coalesced uint2
#pragma unroll
    for (int qi = 0; qi < 4; ++qi) {
      const int m = qi * 16 + col;
      h2 lo, hi;
      lo[0] = (_Float16)acc[qi][0]; lo[1] = (_Float16)acc[qi][1];
      hi[0] = (_Float16)acc[qi][2]; hi[1] = (_Float16)acc[qi][3];
      uint2 pk = {__builtin_bit_cast(unsigned int, lo), __builtin_bit_cast(unsigned int, hi)};
      *(uint2*)(Zbt + (size_t)m * N_ROWS + nt + g * 4) = pk;
    }
  }
}

// ================ ss: SS[t] = (w_t.*Z)^T Z  (+B via ones-MFMA) ================
// 512 blocks x 512 thr (8 waves, wave = 1 ctx). XCD-paired mapping:
// (bid, bid+8) share ns (same Zbt slice) and the same XCD -> L2 reuse.
#define NCH 16
template <bool PARTIAL>
__global__ __launch_bounds__(512, 4) void ss_kernel(
    const _Float16* __restrict__ Zbt, const _Float16* __restrict__ Wt,
    float* __restrict__ SS, float* __restrict__ Bm,
    unsigned short* __restrict__ Pss)
{
  __shared__ __align__(16) _Float16 Zl[4][64 * 64];   // 8KB per buf
  __shared__ __align__(16) _Float16 Wlds[8 * 1024];   // [wave ctx][1024 n] 16KB
  const int tid = threadIdx.x;
  const int l   = tid & 63;
  const int wv  = tid >> 6;
  const int g   = l >> 4;
  const int col = l & 15;
  const int x   = blockIdx.x;
  const int cg  = (x >> 3) & 1;
  const int ns  = (x & 7) | ((x >> 4) << 3);
  const int ctx = cg * 8 + wv;
  const int n0b = ns * 1024;

  f32x4 acc[4][4];
  f32x4 accB[4];
#pragma unroll
  for (int a = 0; a < 4; ++a) {
    accB[a] = (f32x4){0.f, 0.f, 0.f, 0.f};
#pragma unroll
    for (int b = 0; b < 4; ++b) acc[a][b] = (f32x4){0.f, 0.f, 0.f, 0.f};
  }
  FR ones;
#pragma unroll
  for (int j = 0; j < 4; ++j) ones.h[j] = (h2){(_Float16)1.f, (_Float16)1.f};

#pragma unroll
  for (int k = 0; k < 2; ++k) {
    const _Float16* wsrc = Wt + (size_t)ctx * N_ROWS + n0b + k * 512 + l * 8;
    __builtin_amdgcn_global_load_lds((const unsigned int*)wsrc,
        (unsigned int*)((char*)Wlds + wv * 2048 + k * 1024), 16, 0, 0);
  }
  const int zrow  = 8 * wv + (l >> 3);
  const int zslot = l & 7;
  auto stage = [&](int c) {
    const int n0 = n0b + c * 64;
    const _Float16* src = Zbt + (size_t)zrow * N_ROWS + n0 + 8 * (zslot ^ (zrow & 7));
    __builtin_amdgcn_global_load_lds((const unsigned int*)src,
        (unsigned int*)((char*)&Zl[c & 3][0] + wv * 1024 + l * 16), 16, 0, 0);
  };

  stage(0); stage(1); stage(2);
  WAITVM(2);
  SBAR();

  for (int c = 0; c < NCH; ++c) {
    if (c + 3 < NCH) stage(c + 3);
    const char* zb = (const char*)&Zl[c & 3][0];
    const char* wb = (const char*)Wlds + wv * 2048 + c * 128;
#pragma unroll
    for (int s = 0; s < 2; ++s) {
      FR wfr;
      wfr.u = *(const uint4*)(wb + s * 64 + g * 16);
      FR fr[4];
#pragma unroll
      for (int qi = 0; qi < 4; ++qi) {
        const int r = qi * 16 + col;
        fr[qi].u = *(const uint4*)(zb + r * 128 + 16 * ((s * 4 + g) ^ (r & 7)));
      }
      __builtin_amdgcn_s_setprio(1);
#pragma unroll
      for (int qi = 0; qi < 4; ++qi) {
        FR A;
#pragma unroll
        for (int j = 0; j < 4; ++j) A.h[j] = fr[qi].h[j] * wfr.h[j];
        accB[qi] = __builtin_amdgcn_mfma_f32_16x16x32_f16(A.v, ones.v, accB[qi], 0, 0, 0);
#pragma unroll
        for (int ki = 0; ki < 4; ++ki)
          acc[qi][ki] = __builtin_amdgcn_mfma_f32_16x16x32_f16(A.v, fr[ki].v, acc[qi][ki], 0, 0, 0);
      }
      __builtin_amdgcn_s_setprio(0);
    }
    if (c + 3 < NCH)       { WAITVM(2); SBAR(); }
    else if (c == NCH - 3) { WAITVM(1); SBAR(); }
    else if (c == NCH - 2) { WAITVM(0); SBAR(); }
  }

  if (col == 0) {
#pragma unroll
    for (int qi = 0; qi < 4; ++qi)
#pragma unroll
      for (int i = 0; i < 4; ++i)
        atomicAdd(&Bm[ctx * 64 + qi * 16 + g * 4 + i], accB[qi][i]);
  }
  if (PARTIAL) {
    unsigned short* P = Pss + ((size_t)ns * 16 + ctx) * 4096;
#pragma unroll
    for (int qi = 0; qi < 4; ++qi)
#pragma unroll
      for (int ki = 0; ki < 4; ++ki)
#pragma unroll
        for (int i = 0; i < 4; ++i)
          P[(qi * 16 + g * 4 + i) * 64 + ki * 16 + col] = f2bf(acc[qi][ki][i]);
  } else {
#pragma unroll
    for (int qi = 0; qi < 4; ++qi)
#pragma unroll
      for (int ki = 0; ki < 4; ++ki)
#pragma unroll
        for (int i = 0; i < 4; ++i)
          atomicAdd(&SS[(size_t)ctx * 4096 + (qi * 16 + g * 4 + i) * 64 + ki * 16 + col],
                    acc[qi][ki][i]);
  }
}

// ================ fin1: reduce partials + per-context loss_t ================
// 16 blocks (t) x 1024 thr.
template <bool PARTIAL>
__global__ __launch_bounds__(1024) void fin1_kernel(
    const unsigned short* __restrict__ Pss, const float* __restrict__ SSg,
    const float* __restrict__ Bm, const float* __restrict__ wsum,
    const float* __restrict__ Cp, const float* __restrict__ emaS,
    const unsigned char* __restrict__ inited, float* __restrict__ LT)
{
  __shared__ float SSl[4096];
  __shared__ float muL[64], stdL[64];
  __shared__ float red[16];
  const int t = blockIdx.x, tid = threadIdx.x;
  if (PARTIAL) {
    float s0 = 0.f, s1 = 0.f, s2 = 0.f, s3 = 0.f;
    const unsigned short* P = Pss + (size_t)t * 4096 + tid * 4;
#pragma unroll 4
    for (int b = 0; b < 256; ++b) {
      uint2 v = *(const uint2*)(P + (size_t)b * 65536);
      s0 += bf2f((unsigned short)(v.x & 0xffffu));
      s1 += bf2f((unsigned short)(v.x >> 16));
      s2 += bf2f((unsigned short)(v.y & 0xffffu));
      s3 += bf2f((unsigned short)(v.y >> 16));
    }
    SSl[tid * 4 + 0] = s0; SSl[tid * 4 + 1] = s1;
    SSl[tid * 4 + 2] = s2; SSl[tid * 4 + 3] = s3;
  } else {
    float4 v = *(const float4*)(SSg + (size_t)t * 4096 + tid * 4);
    *(float4*)&SSl[tid * 4] = v;
  }
  __syncthreads();
  const float ws  = wsum[t * 16];
  const float inv = 1.0f / ws;
  if (tid < 64) {
    const int m = tid;
    float mu  = Bm[t * 64 + m] * inv;
    float Smm = SSl[m * 65] * inv - mu * mu;
    float de  = 0.9f * emaS[(size_t)t * 4096 + m * 65] + 0.1f * Smm;
    float sq  = inited[t] ? de : Smm;
    muL[m]  = mu;
    stdL[m] = sqrtf(sq + 1e-6f);
  }
  __syncthreads();
  const int m  = tid >> 4;
  const int k0 = (tid & 15) * 4;
  float4 cp4 = *(const float4*)(Cp + (size_t)t * 4096 + tid * 4);
  const float* cpp = (const float*)&cp4;
  float acc = 0.f;
#pragma unroll
  for (int j = 0; j < 4; ++j) {
    const int k = k0 + j;
    float Sig = SSl[m * 64 + k] * inv - muL[m] * muL[k];
    float den = stdL[m] * stdL[k] + 1e-6f;
    float ch  = fminf(1.f, fmaxf(-1.f, Sig / den));
    float d   = ch - cpp[j];
    acc = fmaf(d, d, acc);
  }
#pragma unroll
  for (int o = 1; o < 64; o <<= 1) acc += __shfl_xor(acc, o);
  if ((tid & 63) == 0) red[tid >> 6] = acc;
  __syncthreads();
  if (tid == 0) {
    float s = 0.f;
#pragma unroll
    for (int i = 0; i < 16; ++i) s += red[i];
    LT[t] = s * inv;
  }
}

// ================ fin2: scalar ================
__global__ __launch_bounds__(64) void fin2_kernel(
    const float* __restrict__ LT, const float* __restrict__ wsum,
    float* __restrict__ out)
{
  const int l = threadIdx.x;
  float lt = 0.f, act = 0.f;
  if (l < 16) {
    float ws = wsum[l * 16];
    if (ws >= 30.0f) { act = 1.f; lt = LT[l]; }
  }
#pragma unroll
  for (int o = 1; o < 16; o <<= 1) {
    lt  += __shfl_xor(lt, o);
    act += __shfl_xor(act, o);
  }
  if (l == 0) out[0] = (act > 0.f) ? (0.1f * 1.0f * lt / act) : 0.f;
}

extern "C" void kernel_launch(void* const* d_in, const int* in_sizes, int n_in,
                              void* d_out, int out_size, void* d_ws, size_t ws_size,
                              hipStream_t stream) {
  (void)in_sizes; (void)n_in; (void)out_size;
  const float* Y    = (const float*)d_in[0];
  const float* W    = (const float*)d_in[1];
  const float* Mp   = (const float*)d_in[2];
  const float* Cp   = (const float*)d_in[3];
  const float* emaS = (const float*)d_in[4];
  const unsigned char* inited = (const unsigned char*)d_in[6];
  float* out = (float*)d_out;
  char* ws = (char*)d_ws;
  _Float16* Zbt = (_Float16*)(ws + ZB_OFF);
  _Float16* Wt  = (_Float16*)(ws + WT_OFF);
  float* SS   = (float*)(ws + SS_OFF);
  float* Bm   = (float*)(ws + B_OFF);
  float* wsum = (float*)(ws + WSUM_OFF);
  float* LT   = (float*)(ws + LT_OFF);
  unsigned short* Pss = (unsigned short*)(ws + PSS_OFF);

  if (ws_size >= NEED_BIG) {
    (void)hipMemsetAsync(ws + B_OFF, 0, B_BYTES + WSUM_BYTES, stream);
    zkw_kernel<<<N_ROWS / 128, 256, 0, stream>>>(Y, Mp, W, Zbt, Wt, wsum);
    ss_kernel<true><<<512, 512, 0, stream>>>(Zbt, Wt, SS, Bm, Pss);
    fin1_kernel<true><<<16, 1024, 0, stream>>>(Pss, SS, Bm, wsum, Cp, emaS, inited, LT);
  } else {
    (void)hipMemsetAsync(ws + SS_OFF, 0, SS_BYTES + B_BYTES + WSUM_BYTES, stream);
    zkw_kernel<<<N_ROWS / 128, 256, 0, stream>>>(Y, Mp, W, Zbt, Wt, wsum);
    ss_kernel<false><<<512, 512, 0, stream>>>(Zbt, Wt, SS, Bm, Pss);
    fin1_kernel<false><<<16, 1024, 0, stream>>>(Pss, SS, Bm, wsum, Cp, emaS, inited, LT);
  }
  fin2_kernel<<<1, 64, 0, stream>>>(LT, wsum, out);
}

// Round 11
// 144.018 us; speedup vs baseline: 1.3606x; 1.0594x over previous
//
#include <hip/hip_runtime.h>
#include <stdint.h>

#define N_ROWS 262144
#define D_OUTC 128
#define M_MOD  64
#define T_CTX  16

// ---- workspace layout (bytes) ----
#define ZB_OFF   ((size_t)0)
#define ZB_BYTES ((size_t)M_MOD * N_ROWS * 2)          // Zbt[m][n] f16  33.5MB
#define WT_OFF   (ZB_OFF + ZB_BYTES)
#define WT_BYTES ((size_t)T_CTX * N_ROWS * 2)          // Wt[t][n] f16  8.4MB
#define SS_OFF   (WT_OFF + WT_BYTES)
#define SS_BYTES ((size_t)T_CTX * M_MOD * M_MOD * 4)
#define B_OFF    (SS_OFF + SS_BYTES)
#define B_BYTES  ((size_t)T_CTX * M_MOD * 4)
#define WSUM_OFF (B_OFF + B_BYTES)
#define WSUM_BYTES ((size_t)1024)                      // wsum[t] at stride-16 f32
#define LT_OFF   (WSUM_OFF + WSUM_BYTES)
#define LT_BYTES ((size_t)64)
#define PSS_OFF  (LT_OFF + LT_BYTES)
#define PSS_BYTES ((size_t)256 * T_CTX * M_MOD * M_MOD * 2)  // 33.5MB bf16 partials
#define NEED_BIG (PSS_OFF + PSS_BYTES)

typedef __attribute__((ext_vector_type(4))) float f32x4;
typedef __attribute__((ext_vector_type(8))) _Float16 f16x8;
typedef __attribute__((ext_vector_type(2))) _Float16 h2;

union FR { uint4 u; f16x8 v; h2 h[4]; };

__device__ __forceinline__ float bf2f(unsigned short u) {
  return __uint_as_float(((unsigned int)u) << 16);
}
__device__ __forceinline__ unsigned short f2bf(float f) {
  unsigned int x = __float_as_uint(f);
  return (unsigned short)((x + 0x7fffu + ((x >> 16) & 1u)) >> 16);
}
__device__ __forceinline__ h2 cvt_pkrtz(float a, float b) {
  return __builtin_bit_cast(h2, __builtin_amdgcn_cvt_pkrtz(a, b));
}

#define WAITVM(N) asm volatile("s_waitcnt vmcnt(" #N ")" ::: "memory")
#define SBAR() do { __builtin_amdgcn_s_barrier(); __builtin_amdgcn_sched_barrier(0); } while (0)

// ================ wtr: W[N][16] f32 -> Wt[16][N] f16, + wsum fold ================
__global__ __launch_bounds__(256) void wtr_kernel(const float* __restrict__ W,
                                                  _Float16* __restrict__ Wt,
                                                  float* __restrict__ wsum)
{
  __shared__ float Wf[16][260];
  const int tid = threadIdx.x;
  const int n0  = blockIdx.x * 256;
  {
    const float4* src = (const float4*)(W + (size_t)(n0 + tid) * T_CTX);
#pragma unroll
    for (int q = 0; q < 4; ++q) {
      float4 v = src[q];
      Wf[q * 4 + 0][tid] = v.x; Wf[q * 4 + 1][tid] = v.y;
      Wf[q * 4 + 2][tid] = v.z; Wf[q * 4 + 3][tid] = v.w;
    }
  }
  __syncthreads();
  const int t = tid >> 4, c0 = (tid & 15) * 16;
  FR o[2];
  float s = 0.f;
#pragma unroll
  for (int j = 0; j < 2; ++j)
#pragma unroll
    for (int p = 0; p < 4; ++p) {
      float a = Wf[t][c0 + j * 8 + 2 * p], b = Wf[t][c0 + j * 8 + 2 * p + 1];
      o[j].h[p] = cvt_pkrtz(a, b);
      s += a + b;
    }
  uint4* dst = (uint4*)(Wt + (size_t)t * N_ROWS + n0 + c0);
  dst[0] = o[0].u; dst[1] = o[1].u;
  s += __shfl_xor(s, 1); s += __shfl_xor(s, 2);
  s += __shfl_xor(s, 4); s += __shfl_xor(s, 8);
  if ((tid & 15) == 0) atomicAdd(&wsum[t * 16], s);
}

// ================ zk: Z^T f16 via MFMA, all Y loads hoisted (16 in flight) ====
// 2048 blocks x 256 thr (4 waves), 128 n per block. LDS = Mpl only.
__global__ __launch_bounds__(256, 4) void zk_kernel(
    const float* __restrict__ Y, const float* __restrict__ Mp,
    _Float16* __restrict__ Zbt)
{
  __shared__ __align__(16) _Float16 Mpl[64 * 128];  // 256B/row, 16B slots swizzled by m&7
  const int tid = threadIdx.x;
  const int l   = tid & 63;
  const int wv  = tid >> 6;
  const int g   = l >> 4;
  const int col = l & 15;
  const int n0  = blockIdx.x * 128;

  // ---- Mpl: f32 -> f16 swizzled ----
  {
    const int m  = tid >> 2;
    const int dq = tid & 3;
#pragma unroll
    for (int i = 0; i < 4; ++i) {
      const int s = dq * 4 + i;
      const float* mp = Mp + (size_t)m * D_OUTC + s * 8;
      float4 a = *(const float4*)mp;
      float4 b = *(const float4*)(mp + 4);
      FR o;
      o.h[0] = cvt_pkrtz(a.x, a.y); o.h[1] = cvt_pkrtz(a.z, a.w);
      o.h[2] = cvt_pkrtz(b.x, b.y); o.h[3] = cvt_pkrtz(b.z, b.w);
      const int ss2 = (s & ~7) | ((s & 7) ^ (m & 7));
      *(uint4*)((char*)Mpl + m * 256 + ss2 * 16) = o.u;
    }
  }
  // ---- hoist ALL Y loads (2 tiles x 8 float4) ----
  const int nt0 = n0 + wv * 16;
  const int nt1 = n0 + 64 + wv * 16;
  const float* __restrict__ yr0 = Y + (size_t)(nt0 + col) * D_OUTC;
  const float* __restrict__ yr1 = Y + (size_t)(nt1 + col) * D_OUTC;
  float4 yv0[8], yv1[8];
#pragma unroll
  for (int ks = 0; ks < 4; ++ks) {
    yv0[2 * ks]     = *(const float4*)(yr0 + ks * 32 + g * 8);
    yv0[2 * ks + 1] = *(const float4*)(yr0 + ks * 32 + g * 8 + 4);
  }
#pragma unroll
  for (int ks = 0; ks < 4; ++ks) {
    yv1[2 * ks]     = *(const float4*)(yr1 + ks * 32 + g * 8);
    yv1[2 * ks + 1] = *(const float4*)(yr1 + ks * 32 + g * 8 + 4);
  }
  __syncthreads();   // Mpl ready

#pragma unroll
  for (int it = 0; it < 2; ++it) {
    const float4* yv = (it == 0) ? yv0 : yv1;
    const int nt = (it == 0) ? nt0 : nt1;
    f32x4 acc[4];
#pragma unroll
    for (int qi = 0; qi < 4; ++qi) acc[qi] = (f32x4){0.f, 0.f, 0.f, 0.f};
#pragma unroll
    for (int ks = 0; ks < 4; ++ks) {
      const float* f0 = (const float*)&yv[2 * ks];
      const float* f1 = (const float*)&yv[2 * ks + 1];
      FR Yf;
      Yf.h[0] = cvt_pkrtz(f0[0], f0[1]); Yf.h[1] = cvt_pkrtz(f0[2], f0[3]);
      Yf.h[2] = cvt_pkrtz(f1[0], f1[1]); Yf.h[3] = cvt_pkrtz(f1[2], f1[3]);
#pragma unroll
      for (int qi = 0; qi < 4; ++qi) {
        const int m = qi * 16 + col;
        const int s = ks * 4 + g;
        FR Mf;
        Mf.u = *(const uint4*)((char*)Mpl + m * 256 + 16 * ((s & ~7) | ((s & 7) ^ (m & 7))));
        acc[qi] = __builtin_amdgcn_mfma_f32_16x16x32_f16(Yf.v, Mf.v, acc[qi], 0, 0, 0);
      }
    }
#pragma unroll
    for (int qi = 0; qi < 4; ++qi) {
      const int m = qi * 16 + col;
      h2 lo, hi;
      lo[0] = (_Float16)acc[qi][0]; lo[1] = (_Float16)acc[qi][1];
      hi[0] = (_Float16)acc[qi][2]; hi[1] = (_Float16)acc[qi][3];
      uint2 pk = {__builtin_bit_cast(unsigned int, lo), __builtin_bit_cast(unsigned int, hi)};
      *(uint2*)(Zbt + (size_t)m * N_ROWS + nt + g * 4) = pk;
    }
  }
}

// ================ ss: SS[t] = (w_t.*Z)^T Z  (+B via ones-MFMA) ================
// 512 blocks x 512 thr (8 waves, wave = 1 ctx). (bid, bid+8) share ns + XCD.
#define NCH 16
template <bool PARTIAL>
__global__ __launch_bounds__(512, 4) void ss_kernel(
    const _Float16* __restrict__ Zbt, const _Float16* __restrict__ Wt,
    float* __restrict__ SS, float* __restrict__ Bm,
    unsigned short* __restrict__ Pss)
{
  __shared__ __align__(16) _Float16 Zl[4][64 * 64];   // 8KB per buf
  __shared__ __align__(16) _Float16 Wlds[8 * 1024];   // 16KB
  const int tid = threadIdx.x;
  const int l   = tid & 63;
  const int wv  = tid >> 6;
  const int g   = l >> 4;
  const int col = l & 15;
  const int x   = blockIdx.x;
  const int cg  = (x >> 3) & 1;
  const int ns  = (x & 7) | ((x >> 4) << 3);
  const int ctx = cg * 8 + wv;
  const int n0b = ns * 1024;

  f32x4 acc[4][4];
  f32x4 accB[4];
#pragma unroll
  for (int a = 0; a < 4; ++a) {
    accB[a] = (f32x4){0.f, 0.f, 0.f, 0.f};
#pragma unroll
    for (int b = 0; b < 4; ++b) acc[a][b] = (f32x4){0.f, 0.f, 0.f, 0.f};
  }
  FR ones;
#pragma unroll
  for (int j = 0; j < 4; ++j) ones.h[j] = (h2){(_Float16)1.f, (_Float16)1.f};

#pragma unroll
  for (int k = 0; k < 2; ++k) {
    const _Float16* wsrc = Wt + (size_t)ctx * N_ROWS + n0b + k * 512 + l * 8;
    __builtin_amdgcn_global_load_lds((const unsigned int*)wsrc,
        (unsigned int*)((char*)Wlds + wv * 2048 + k * 1024), 16, 0, 0);
  }
  const int zrow  = 8 * wv + (l >> 3);
  const int zslot = l & 7;
  auto stage = [&](int c) {
    const int n0 = n0b + c * 64;
    const _Float16* src = Zbt + (size_t)zrow * N_ROWS + n0 + 8 * (zslot ^ (zrow & 7));
    __builtin_amdgcn_global_load_lds((const unsigned int*)src,
        (unsigned int*)((char*)&Zl[c & 3][0] + wv * 1024 + l * 16), 16, 0, 0);
  };

  stage(0); stage(1); stage(2);
  WAITVM(2);
  SBAR();

  for (int c = 0; c < NCH; ++c) {
    if (c + 3 < NCH) stage(c + 3);
    const char* zb = (const char*)&Zl[c & 3][0];
    const char* wb = (const char*)Wlds + wv * 2048 + c * 128;
#pragma unroll
    for (int s = 0; s < 2; ++s) {
      FR wfr;
      wfr.u = *(const uint4*)(wb + s * 64 + g * 16);
      FR fr[4];
#pragma unroll
      for (int qi = 0; qi < 4; ++qi) {
        const int r = qi * 16 + col;
        fr[qi].u = *(const uint4*)(zb + r * 128 + 16 * ((s * 4 + g) ^ (r & 7)));
      }
      __builtin_amdgcn_s_setprio(1);
#pragma unroll
      for (int qi = 0; qi < 4; ++qi) {
        FR A;
#pragma unroll
        for (int j = 0; j < 4; ++j) A.h[j] = fr[qi].h[j] * wfr.h[j];
        accB[qi] = __builtin_amdgcn_mfma_f32_16x16x32_f16(A.v, ones.v, accB[qi], 0, 0, 0);
#pragma unroll
        for (int ki = 0; ki < 4; ++ki)
          acc[qi][ki] = __builtin_amdgcn_mfma_f32_16x16x32_f16(A.v, fr[ki].v, acc[qi][ki], 0, 0, 0);
      }
      __builtin_amdgcn_s_setprio(0);
    }
    if (c + 3 < NCH)       { WAITVM(2); SBAR(); }
    else if (c == NCH - 3) { WAITVM(1); SBAR(); }
    else if (c == NCH - 2) { WAITVM(0); SBAR(); }
  }

  if (col == 0) {
#pragma unroll
    for (int qi = 0; qi < 4; ++qi)
#pragma unroll
      for (int i = 0; i < 4; ++i)
        atomicAdd(&Bm[ctx * 64 + qi * 16 + g * 4 + i], accB[qi][i]);
  }
  if (PARTIAL) {
    unsigned short* P = Pss + ((size_t)ns * 16 + ctx) * 4096;
#pragma unroll
    for (int qi = 0; qi < 4; ++qi)
#pragma unroll
      for (int ki = 0; ki < 4; ++ki)
#pragma unroll
        for (int i = 0; i < 4; ++i)
          P[(qi * 16 + g * 4 + i) * 64 + ki * 16 + col] = f2bf(acc[qi][ki][i]);
  } else {
#pragma unroll
    for (int qi = 0; qi < 4; ++qi)
#pragma unroll
      for (int ki = 0; ki < 4; ++ki)
#pragma unroll
        for (int i = 0; i < 4; ++i)
          atomicAdd(&SS[(size_t)ctx * 4096 + (qi * 16 + g * 4 + i) * 64 + ki * 16 + col],
                    acc[qi][ki][i]);
  }
}

// ================ reduce bf16 partials -> SS f32 ================
__global__ __launch_bounds__(256) void ssred_kernel(
    const unsigned short* __restrict__ Pss, float* __restrict__ SS)
{
  const int e = blockIdx.x * 256 + threadIdx.x;
  float s = 0.f;
#pragma unroll 8
  for (int b = 0; b < 256; ++b)
    s += bf2f(Pss[(size_t)b * 65536 + e]);
  SS[e] = s;
}

// ================ finalize ================
__global__ __launch_bounds__(64) void fin1_kernel(
    const float* __restrict__ SS, const float* __restrict__ Bm,
    const float* __restrict__ wsum, const float* __restrict__ Cp,
    const float* __restrict__ emaS, const unsigned char* __restrict__ inited,
    float* __restrict__ LT)
{
  const int t = blockIdx.x, m = threadIdx.x;
  __shared__ float muL[64], stdL[64];
  const float ws  = wsum[t * 16];
  const float inv = 1.0f / ws;
  const float mu  = Bm[t * 64 + m] * inv;
  {
    float Smm = SS[(size_t)t * 4096 + m * 65] * inv - mu * mu;
    float de  = 0.9f * emaS[(size_t)t * 4096 + m * 65] + 0.1f * Smm;
    float sq  = inited[t] ? de : Smm;
    muL[m]  = mu;
    stdL[m] = sqrtf(sq + 1e-6f);
  }
  __syncthreads();
  const float sm = stdL[m];
  const float* SSr = SS + (size_t)t * 4096 + m * 64;
  const float* Cpr = Cp + (size_t)t * 4096 + m * 64;
  float acc = 0.f;
#pragma unroll
  for (int k = 0; k < 64; ++k) {
    float Sig = SSr[k] * inv - mu * muL[k];
    float den = sm * stdL[k] + 1e-6f;
    float ch  = fminf(1.f, fmaxf(-1.f, Sig / den));
    float d   = ch - Cpr[k];
    acc = fmaf(d, d, acc);
  }
#pragma unroll
  for (int o = 1; o < 64; o <<= 1) acc += __shfl_xor(acc, o);
  if (m == 0) LT[t] = acc * inv;
}

__global__ __launch_bounds__(64) void fin2_kernel(
    const float* __restrict__ LT, const float* __restrict__ wsum,
    float* __restrict__ out)
{
  const int l = threadIdx.x;
  float lt = 0.f, act = 0.f;
  if (l < 16) {
    float ws = wsum[l * 16];
    if (ws >= 30.0f) { act = 1.f; lt = LT[l]; }
  }
#pragma unroll
  for (int o = 1; o < 16; o <<= 1) {
    lt  += __shfl_xor(lt, o);
    act += __shfl_xor(act, o);
  }
  if (l == 0) out[0] = (act > 0.f) ? (0.1f * 1.0f * lt / act) : 0.f;
}

extern "C" void kernel_launch(void* const* d_in, const int* in_sizes, int n_in,
                              void* d_out, int out_size, void* d_ws, size_t ws_size,
                              hipStream_t stream) {
  (void)in_sizes; (void)n_in; (void)out_size;
  const float* Y    = (const float*)d_in[0];
  const float* W    = (const float*)d_in[1];
  const float* Mp   = (const float*)d_in[2];
  const float* Cp   = (const float*)d_in[3];
  const float* emaS = (const float*)d_in[4];
  const unsigned char* inited = (const unsigned char*)d_in[6];
  float* out = (float*)d_out;
  char* ws = (char*)d_ws;
  _Float16* Zbt = (_Float16*)(ws + ZB_OFF);
  _Float16* Wt  = (_Float16*)(ws + WT_OFF);
  float* SS   = (float*)(ws + SS_OFF);
  float* Bm   = (float*)(ws + B_OFF);
  float* wsum = (float*)(ws + WSUM_OFF);
  float* LT   = (float*)(ws + LT_OFF);
  unsigned short* Pss = (unsigned short*)(ws + PSS_OFF);

  if (ws_size >= NEED_BIG) {
    (void)hipMemsetAsync(ws + B_OFF, 0, B_BYTES + WSUM_BYTES, stream);
    wtr_kernel<<<N_ROWS / 256, 256, 0, stream>>>(W, Wt, wsum);
    zk_kernel<<<N_ROWS / 128, 256, 0, stream>>>(Y, Mp, Zbt);
    ss_kernel<true><<<512, 512, 0, stream>>>(Zbt, Wt, SS, Bm, Pss);
    ssred_kernel<<<256, 256, 0, stream>>>(Pss, SS);
  } else {
    (void)hipMemsetAsync(ws + SS_OFF, 0, SS_BYTES + B_BYTES + WSUM_BYTES, stream);
    wtr_kernel<<<N_ROWS / 256, 256, 0, stream>>>(W, Wt, wsum);
    zk_kernel<<<N_ROWS / 128, 256, 0, stream>>>(Y, Mp, Zbt);
    ss_kernel<false><<<512, 512, 0, stream>>>(Zbt, Wt, SS, Bm, Pss);
  }
  fin1_kernel<<<16, 64, 0, stream>>>(SS, Bm, wsum, Cp, emaS, inited, LT);
  fin2_kernel<<<1, 64, 0, stream>>>(LT, wsum, out);
}